// Round 5
// baseline (593.726 us; speedup 1.0000x reference)
//
#include <hip/hip_runtime.h>

typedef short short8 __attribute__((ext_vector_type(8)));
typedef float v4f __attribute__((ext_vector_type(4)));

#define LOG2E 1.4426950408889634f

__device__ __forceinline__ unsigned short f2bf(float f) {
  unsigned int u = __float_as_uint(f);
  u += 0x7fff + ((u >> 16) & 1);   // round-to-nearest-even
  return (unsigned short)(u >> 16);
}
__device__ __forceinline__ float b2f(unsigned short h) {
  return __uint_as_float(((unsigned int)h) << 16);
}
__device__ __forceinline__ void gl_lds16(const void* g, void* l) {
  __builtin_amdgcn_global_load_lds((const __attribute__((address_space(1))) void*)g,
                                   (__attribute__((address_space(3))) void*)l, 16, 0, 0);
}

// ---------------- elementwise f32 -> bf16 ----------------
__global__ __launch_bounds__(256) void cvt_f32_bf16(const float* __restrict__ src,
                                                    unsigned short* __restrict__ dst, int n) {
  int i = (blockIdx.x * 256 + threadIdx.x) * 4;
  if (i < n) {
    float4 v = *(const float4*)(src + i);
    ushort4 o;
    o.x = f2bf(v.x); o.y = f2bf(v.y); o.z = f2bf(v.z); o.w = f2bf(v.w);
    *(ushort4*)(dst + i) = o;
  }
}

// ---------------- tiled transpose f32 (K x N) -> bf16 (N x K), dst ld = 2048 ----------------
__global__ __launch_bounds__(256) void transpose_f32_bf16(const float* __restrict__ src,
                                                          unsigned short* __restrict__ dst,
                                                          int srcCols) {
  __shared__ float tile[64][65];
  const int c0 = blockIdx.x * 64;   // src col = dst row
  const int r0 = blockIdx.y * 64;   // src row = dst col
  const int t = threadIdx.x;
#pragma unroll
  for (int i = 0; i < 16; ++i) {
    int idx = t + i * 256; int r = idx >> 6, c = idx & 63;
    tile[r][c] = src[(size_t)(r0 + r) * srcCols + c0 + c];
  }
  __syncthreads();
#pragma unroll
  for (int i = 0; i < 16; ++i) {
    int idx = t + i * 256; int r = idx >> 6, c = idx & 63;
    dst[(size_t)(c0 + r) * 2048 + r0 + c] = f2bf(tile[c][r]);
  }
}

// ---------------- GEMM: C[M,N] = A[M,K] * Bt[N,K]^T  (bf16 in, fp32 acc) ----------------
// Register-direct, barrier-free, no LDS: each wave loads its MFMA A/B fragments straight
// from global with double-buffered registers. All dependencies are register-tracked, so
// the compiler emits fine-grained s_waitcnt vmcnt(N) (AITER-style), never a full drain.
// Each global_load_dwordx4 covers 16 rows x 64 B = 16 full cache lines (no waste).
template <bool OUT_BF16>
__global__ __launch_bounds__(256) void gemm_bt(const unsigned short* __restrict__ A,
                                               const unsigned short* __restrict__ Bt,
                                               void* __restrict__ Cv,
                                               int M, int N, int K) {
  const int t = threadIdx.x;
  const int wave = t >> 6, lane = t & 63, quad = lane >> 4, l16 = lane & 15;
  const int tm = blockIdx.y * 128, tn = blockIdx.x * 128;
  const int wm = (wave >> 1) * 64, wn = (wave & 1) * 64;
  v4f acc[4][4];
#pragma unroll
  for (int i = 0; i < 4; ++i)
#pragma unroll
    for (int j = 0; j < 4; ++j) acc[i][j] = (v4f){0.f, 0.f, 0.f, 0.f};

  const unsigned short* pa[4];
  const unsigned short* pb[4];
#pragma unroll
  for (int i = 0; i < 4; ++i) {
    pa[i] = A + (size_t)(tm + wm + i * 16 + l16) * K + quad * 8;
    pb[i] = Bt + (size_t)(tn + wn + i * 16 + l16) * K + quad * 8;
  }

  short8 a0[4], b0[4], a1[4], b1[4];
#pragma unroll
  for (int i = 0; i < 4; ++i) { a0[i] = *(const short8*)pa[i]; b0[i] = *(const short8*)pb[i]; }

  const int nit = K >> 5;   // K=2048 -> 64 iters (even)
  for (int it = 0; it < nit; it += 2) {
    if (it + 1 < nit) {
#pragma unroll
      for (int i = 0; i < 4; ++i) {
        a1[i] = *(const short8*)(pa[i] + 32);
        b1[i] = *(const short8*)(pb[i] + 32);
      }
    }
#pragma unroll
    for (int mt = 0; mt < 4; ++mt)
#pragma unroll
      for (int nt = 0; nt < 4; ++nt)
        acc[mt][nt] = __builtin_amdgcn_mfma_f32_16x16x32_bf16(a0[mt], b0[nt], acc[mt][nt], 0, 0, 0);

    if (it + 2 < nit) {
#pragma unroll
      for (int i = 0; i < 4; ++i) {
        a0[i] = *(const short8*)(pa[i] + 64);
        b0[i] = *(const short8*)(pb[i] + 64);
        pa[i] += 64; pb[i] += 64;
      }
    }
#pragma unroll
    for (int mt = 0; mt < 4; ++mt)
#pragma unroll
      for (int nt = 0; nt < 4; ++nt)
        acc[mt][nt] = __builtin_amdgcn_mfma_f32_16x16x32_bf16(a1[mt], b1[nt], acc[mt][nt], 0, 0, 0);
  }

#pragma unroll
  for (int mt = 0; mt < 4; ++mt)
#pragma unroll
    for (int nt = 0; nt < 4; ++nt)
#pragma unroll
      for (int r = 0; r < 4; ++r) {
        int row = tm + wm + mt * 16 + quad * 4 + r;
        int col = tn + wn + nt * 16 + l16;
        float v = acc[mt][nt][r];
        if (OUT_BF16) ((unsigned short*)Cv)[(size_t)row * N + col] = f2bf(v);
        else          ((float*)Cv)[(size_t)row * N + col] = v;
      }
}

// ---------------- in-place RoPE on Q (cols 0..2047, pre-scaled by 1/sqrt(HD)) and K ----------------
__global__ __launch_bounds__(256) void rope_k(unsigned short* __restrict__ qkv,
                                              const float* __restrict__ freqs) {
  const int bs = blockIdx.x;          // b*2048 + s
  const int s = bs & 2047;
  const float qscale = 0.08838834764831845f;  // 1/sqrt(128)
  unsigned short* row = qkv + (size_t)bs * 4096;
  for (int idx = threadIdx.x; idx < 1536; idx += 256) {
    int i = idx & 63;                 // pair index within head
    int col; float sc;
    if (idx < 1024) { col = (idx >> 6) * 128 + 2 * i; sc = qscale; }                 // Q heads
    else            { col = 2048 + ((idx - 1024) >> 6) * 128 + 2 * i; sc = 1.0f; }   // K heads
    float c = freqs[s * 128 + 2 * i];
    float sn = freqs[s * 128 + 2 * i + 1];
    float x0 = b2f(row[col]), x1 = b2f(row[col + 1]);
    row[col]     = f2bf((x0 * sn - x1 * c) * sc);
    row[col + 1] = f2bf((x0 * c + x1 * sn) * sc);
  }
}

// ---------------- V transpose: QKV V-cols (b,s,kv,d) -> Vt[(b*8+kv), d, s] ----------------
__global__ __launch_bounds__(256) void transpose_v(const unsigned short* __restrict__ qkv,
                                                   unsigned short* __restrict__ vt) {
  __shared__ unsigned short tile[64][65];
  const int s0 = blockIdx.x * 64, d0 = blockIdx.y * 64;
  const int bk = blockIdx.z; const int b = bk >> 3, kv = bk & 7;
  const int t = threadIdx.x;
#pragma unroll
  for (int i = 0; i < 16; ++i) {
    int idx = t + i * 256; int r = idx >> 6, c = idx & 63;
    tile[r][c] = qkv[(size_t)(b * 2048 + s0 + r) * 4096 + 3072 + kv * 128 + d0 + c];
  }
  __syncthreads();
#pragma unroll
  for (int i = 0; i < 16; ++i) {
    int idx = t + i * 256; int r = idx >> 6, c = idx & 63;
    vt[((size_t)bk * 128 + d0 + r) * 2048 + s0 + c] = tile[c][r];
  }
}

// ---------------- causal flash attention, S^T formulation ----------------
// grid: (16, H, B); block does q-tiles {j, 31-j} (uniform 33 iters). 4 waves; wave w owns
// q rows qtile*64 + w*16 .. +15. LDS K/V tiles chunk-swizzled (chunk ^= row & (nchunk-1)).
__global__ __launch_bounds__(256) void attn_k(const unsigned short* __restrict__ qkv,
                                              const unsigned short* __restrict__ vt,
                                              unsigned short* __restrict__ Ob) {
  __shared__ __align__(16) unsigned short Ks[64 * 128];   // [key][d], 16 chunks/row
  __shared__ __align__(16) unsigned short Vs[128 * 64];   // [d][key],  8 chunks/row
  __shared__ __align__(16) unsigned short Ps[4][16 * 64]; // per-wave P [qrow][key], 8 chunks/row
  const int t = threadIdx.x, wave = t >> 6, lane = t & 63, quad = lane >> 4, l16 = lane & 15;
  const int jpair = blockIdx.x, h = blockIdx.y, b = blockIdx.z;
  const int kv = h >> 1;

  for (int pass = 0; pass < 2; ++pass) {
    const int qblk = (pass == 0) ? jpair : 31 - jpair;
    const int q0 = qblk * 64;

    short8 qf[4];
    {
      const unsigned short* qp =
          qkv + (size_t)(b * 2048 + q0 + wave * 16 + l16) * 4096 + h * 128 + quad * 8;
#pragma unroll
      for (int kc = 0; kc < 4; ++kc) qf[kc] = *(const short8*)(qp + kc * 32);
    }
    v4f oa[8];
#pragma unroll
    for (int i = 0; i < 8; ++i) oa[i] = (v4f){0.f, 0.f, 0.f, 0.f};
    float m_s = -3.0e38f, l_s = 0.f;   // softmax state for qrow = q0 + wave*16 + l16

    for (int jt = 0; jt <= qblk; ++jt) {
      __syncthreads();   // previous iter/pass done reading Ks/Vs
#pragma unroll
      for (int issue = 0; issue < 4; ++issue) {
        int s = issue * 256 + t;
        // K: slot row = s>>4, phys chunk = s&15, source chunk = (s&15)^(row&15)
        gl_lds16(qkv + (size_t)(b * 2048 + jt * 64 + (s >> 4)) * 4096 + 2048 + kv * 128 +
                     (((s & 15) ^ ((s >> 4) & 15)) * 8),
                 Ks + (issue * 256 + wave * 64) * 8);
        // V: slot row(d) = s>>3, phys chunk = s&7, source chunk = (s&7)^(row&7)
        gl_lds16(vt + ((size_t)(b * 8 + kv) * 128 + (s >> 3)) * 2048 + jt * 64 +
                     (((s & 7) ^ ((s >> 3) & 7)) * 8),
                 Vs + (issue * 256 + wave * 64) * 8);
      }
      __syncthreads();

      // S^T = K * Q^T : st[mt] C-layout row=key mt*16+quad*4+r, col=qrow l16
      v4f st[4];
#pragma unroll
      for (int mt = 0; mt < 4; ++mt) st[mt] = (v4f){0.f, 0.f, 0.f, 0.f};
#pragma unroll
      for (int kc = 0; kc < 4; ++kc)
#pragma unroll
        for (int mt = 0; mt < 4; ++mt) {
          short8 kf = *(const short8*)(Ks + (mt * 16 + l16) * 128 + (((kc * 4 + quad) ^ l16) * 8));
          st[mt] = __builtin_amdgcn_mfma_f32_16x16x32_bf16(kf, qf[kc], st[mt], 0, 0, 0);
        }

      // masking (diag tile only) + per-lane max over 16 key values
      const bool diag = (jt == qblk);
      float mx = -3.0e38f;
#pragma unroll
      for (int mt = 0; mt < 4; ++mt)
#pragma unroll
        for (int r = 0; r < 4; ++r) {
          float v = st[mt][r];
          if (diag && (mt * 16 + quad * 4 + r > wave * 16 + l16)) v = -1.0e30f;
          st[mt][r] = v;
          mx = fmaxf(mx, v);
        }
      mx = fmaxf(mx, __shfl_xor(mx, 16));
      mx = fmaxf(mx, __shfl_xor(mx, 32));
      float mn = fmaxf(m_s, mx);
      float alpha = exp2f((m_s - mn) * LOG2E);
      m_s = mn;
      float lt = 0.f;
#pragma unroll
      for (int mt = 0; mt < 4; ++mt)
#pragma unroll
        for (int r = 0; r < 4; ++r) {
          float p = exp2f((st[mt][r] - mn) * LOG2E);
          st[mt][r] = p;
          lt += p;
        }
      lt += __shfl_xor(lt, 16);
      lt += __shfl_xor(lt, 32);
      l_s = l_s * alpha + lt;

      // rescale O accumulator: alpha indexed by qrow_rel; oa rows are quad*4+r
      float a_q[4];
#pragma unroll
      for (int r = 0; r < 4; ++r) a_q[r] = __shfl(alpha, quad * 4 + r);
#pragma unroll
      for (int nt = 0; nt < 8; ++nt)
#pragma unroll
        for (int r = 0; r < 4; ++r) oa[nt][r] *= a_q[r];

      // P^T (C-layout) -> P [qrow][key] in LDS, packed b64 writes, swizzled
#pragma unroll
      for (int mt = 0; mt < 4; ++mt) {
        int pcp = ((mt * 2 + (quad >> 1)) ^ (l16 & 7));
        ushort4 w;
        w.x = f2bf(st[mt][0]); w.y = f2bf(st[mt][1]);
        w.z = f2bf(st[mt][2]); w.w = f2bf(st[mt][3]);
        *(ushort4*)(&Ps[wave][l16 * 64 + pcp * 8 + (quad & 1) * 4]) = w;
      }
      asm volatile("s_waitcnt lgkmcnt(0)" ::: "memory");   // same-wave DS ordering

      short8 pf[2];
#pragma unroll
      for (int kc2 = 0; kc2 < 2; ++kc2)
        pf[kc2] = *(const short8*)(&Ps[wave][l16 * 64 + (((kc2 * 4 + quad) ^ (l16 & 7)) * 8)]);
#pragma unroll
      for (int nt = 0; nt < 8; ++nt)
#pragma unroll
        for (int kc2 = 0; kc2 < 2; ++kc2) {
          short8 vf = *(const short8*)(Vs + (nt * 16 + l16) * 64 +
                                       (((kc2 * 4 + quad) ^ (l16 & 7)) * 8));
          oa[nt] = __builtin_amdgcn_mfma_f32_16x16x32_bf16(pf[kc2], vf, oa[nt], 0, 0, 0);
        }
    }

    // epilogue: l indexed by qrow_rel (l16 lane-space) -> rows quad*4+r
    float inv[4];
#pragma unroll
    for (int r = 0; r < 4; ++r) inv[r] = 1.0f / __shfl(l_s, quad * 4 + r);
#pragma unroll
    for (int r = 0; r < 4; ++r) {
      int row = b * 2048 + q0 + wave * 16 + quad * 4 + r;
#pragma unroll
      for (int nt = 0; nt < 8; ++nt)
        Ob[(size_t)row * 2048 + h * 128 + nt * 16 + l16] = f2bf(oa[nt][r] * inv[r]);
    }
    __syncthreads();   // protect Ks/Vs before next pass begins staging
  }
}

extern "C" void kernel_launch(void* const* d_in, const int* in_sizes, int n_in,
                              void* d_out, int out_size, void* d_ws, size_t ws_size,
                              hipStream_t stream) {
  (void)in_sizes; (void)n_in; (void)out_size; (void)ws_size;
  const float* x  = (const float*)d_in[0];
  const float* fr = (const float*)d_in[1];
  // d_in[2] = mask: implemented as causal directly
  const float* wq = (const float*)d_in[3];
  const float* wk = (const float*)d_in[4];
  const float* wv = (const float*)d_in[5];
  const float* wo = (const float*)d_in[6];
  float* out = (float*)d_out;

  char* ws = (char*)d_ws;
  unsigned short* Xb    = (unsigned short*)(ws);                      // 16 MB
  unsigned short* WqkvT = (unsigned short*)(ws + (size_t)(16u << 20));// 16 MB, [n][k]
  unsigned short* WoT   = (unsigned short*)(ws + (size_t)(32u << 20));// 8 MB
  unsigned short* QKV   = (unsigned short*)(ws + (size_t)(40u << 20));// 32 MB (4096 x 4096)
  unsigned short* Vt    = (unsigned short*)(ws);                      // reuse Xb region
  unsigned short* Ob    = (unsigned short*)(ws + (size_t)(16u << 20));// reuse WqkvT region

  cvt_f32_bf16<<<8192, 256, 0, stream>>>(x, Xb, 2 * 2048 * 2048);
  transpose_f32_bf16<<<dim3(32, 32), 256, 0, stream>>>(wq, WqkvT, 2048);
  transpose_f32_bf16<<<dim3(16, 32), 256, 0, stream>>>(wk, WqkvT + (size_t)2048 * 2048, 1024);
  transpose_f32_bf16<<<dim3(16, 32), 256, 0, stream>>>(wv, WqkvT + (size_t)3072 * 2048, 1024);
  transpose_f32_bf16<<<dim3(32, 32), 256, 0, stream>>>(wo, WoT, 2048);
  gemm_bt<true><<<dim3(32, 32), 256, 0, stream>>>(Xb, WqkvT, QKV, 4096, 4096, 2048);
  rope_k<<<4096, 256, 0, stream>>>(QKV, fr);
  transpose_v<<<dim3(32, 2, 16), 256, 0, stream>>>(QKV, Vt);
  attn_k<<<dim3(16, 16, 2), 256, 0, stream>>>(QKV, Vt, Ob);
  gemm_bt<false><<<dim3(16, 32), 256, 0, stream>>>(Ob, WoT, out, 4096, 2048, 2048);
}

// Round 8
// 383.806 us; speedup vs baseline: 1.5469x; 1.5469x over previous
//
#include <hip/hip_runtime.h>

typedef short short8 __attribute__((ext_vector_type(8)));
typedef float v4f __attribute__((ext_vector_type(4)));

#define LOG2E 1.4426950408889634f

__device__ __forceinline__ unsigned short f2bf(float f) {
  unsigned int u = __float_as_uint(f);
  u += 0x7fff + ((u >> 16) & 1);   // round-to-nearest-even
  return (unsigned short)(u >> 16);
}
__device__ __forceinline__ float b2f(unsigned short h) {
  return __uint_as_float(((unsigned int)h) << 16);
}
__device__ __forceinline__ void gl_lds16(const void* g, void* l) {
  __builtin_amdgcn_global_load_lds((const __attribute__((address_space(1))) void*)g,
                                   (__attribute__((address_space(3))) void*)l, 16, 0, 0);
}

// ---------------- elementwise f32 -> bf16 ----------------
__global__ __launch_bounds__(256) void cvt_f32_bf16(const float* __restrict__ src,
                                                    unsigned short* __restrict__ dst, int n) {
  int i = (blockIdx.x * 256 + threadIdx.x) * 4;
  if (i < n) {
    float4 v = *(const float4*)(src + i);
    ushort4 o;
    o.x = f2bf(v.x); o.y = f2bf(v.y); o.z = f2bf(v.z); o.w = f2bf(v.w);
    *(ushort4*)(dst + i) = o;
  }
}

// ---------------- tiled transpose f32 (K x N) -> bf16 (N x K), dst ld = 2048 ----------------
__global__ __launch_bounds__(256) void transpose_f32_bf16(const float* __restrict__ src,
                                                          unsigned short* __restrict__ dst,
                                                          int srcCols) {
  __shared__ float tile[64][65];
  const int c0 = blockIdx.x * 64;   // src col = dst row
  const int r0 = blockIdx.y * 64;   // src row = dst col
  const int t = threadIdx.x;
#pragma unroll
  for (int i = 0; i < 16; ++i) {
    int idx = t + i * 256; int r = idx >> 6, c = idx & 63;
    tile[r][c] = src[(size_t)(r0 + r) * srcCols + c0 + c];
  }
  __syncthreads();
#pragma unroll
  for (int i = 0; i < 16; ++i) {
    int idx = t + i * 256; int r = idx >> 6, c = idx & 63;
    dst[(size_t)(c0 + r) * 2048 + r0 + c] = f2bf(tile[c][r]);
  }
}

// ---------------- GEMM: C[M,N] = A[M,K] * Bt[N,K]^T  (bf16 in, fp32 acc) ----------------
// R3-proven version: double-buffered LDS, one barrier per K-iter:
// sync -> issue stage(it+1) -> compute(it).
// LDS chunk-swizzle: physical chunk p at row holds logical chunk p ^ ((row>>1)&3)
template <bool OUT_BF16>
__global__ __launch_bounds__(256) void gemm_bt(const unsigned short* __restrict__ A,
                                               const unsigned short* __restrict__ Bt,
                                               void* __restrict__ Cv,
                                               int M, int N, int K) {
  __shared__ __align__(16) unsigned short As[2][128 * 32];
  __shared__ __align__(16) unsigned short Bs[2][128 * 32];
  const int t = threadIdx.x;
  const int wave = t >> 6, lane = t & 63, quad = lane >> 4, l16 = lane & 15;
  const int tm = blockIdx.y * 128, tn = blockIdx.x * 128;
  const int wm = (wave >> 1) * 64, wn = (wave & 1) * 64;
  v4f acc[4][4];
#pragma unroll
  for (int i = 0; i < 4; ++i)
#pragma unroll
    for (int j = 0; j < 4; ++j) acc[i][j] = (v4f){0.f, 0.f, 0.f, 0.f};

  const int swz = (l16 >> 1) & 3;   // (row>>1)&3 for rows wm+mt*16+l16

  // per-thread staging source pointers (slot s: row = s>>2, phys chunk = s&3,
  // logical/source chunk = (s&3)^((s>>3)&3))
  const int s0 = t, s1 = 256 + t;
  const unsigned short* pa0 = A + (size_t)(tm + (s0 >> 2)) * K + ((s0 & 3) ^ ((s0 >> 3) & 3)) * 8;
  const unsigned short* pa1 = A + (size_t)(tm + (s1 >> 2)) * K + ((s1 & 3) ^ ((s1 >> 3) & 3)) * 8;
  const unsigned short* pb0 = Bt + (size_t)(tn + (s0 >> 2)) * K + ((s0 & 3) ^ ((s0 >> 3) & 3)) * 8;
  const unsigned short* pb1 = Bt + (size_t)(tn + (s1 >> 2)) * K + ((s1 & 3) ^ ((s1 >> 3) & 3)) * 8;
  const int dOff0 = (wave * 64) * 8;          // shorts
  const int dOff1 = (256 + wave * 64) * 8;

  // prologue: stage it=0 into buf 0
  gl_lds16(pa0, &As[0][dOff0]); gl_lds16(pa1, &As[0][dOff1]);
  gl_lds16(pb0, &Bs[0][dOff0]); gl_lds16(pb1, &Bs[0][dOff1]);
  pa0 += 32; pa1 += 32; pb0 += 32; pb1 += 32;

  const int nit = K >> 5;
  for (int it = 0; it < nit; ++it) {
    __syncthreads();   // all waves done reading buf[it-1 & 1]; own stage(it) drained (vmcnt0)
    const int cur = it & 1;
    if (it + 1 < nit) {
      const int nxt = cur ^ 1;
      gl_lds16(pa0, &As[nxt][dOff0]); gl_lds16(pa1, &As[nxt][dOff1]);
      gl_lds16(pb0, &Bs[nxt][dOff0]); gl_lds16(pb1, &Bs[nxt][dOff1]);
      pa0 += 32; pa1 += 32; pb0 += 32; pb1 += 32;
    }
    short8 af[4], bf[4];
#pragma unroll
    for (int mt = 0; mt < 4; ++mt)
      af[mt] = *(const short8*)(&As[cur][(wm + mt * 16 + l16) * 32 + (quad ^ swz) * 8]);
#pragma unroll
    for (int nt = 0; nt < 4; ++nt)
      bf[nt] = *(const short8*)(&Bs[cur][(wn + nt * 16 + l16) * 32 + (quad ^ swz) * 8]);
#pragma unroll
    for (int mt = 0; mt < 4; ++mt)
#pragma unroll
      for (int nt = 0; nt < 4; ++nt)
        acc[mt][nt] = __builtin_amdgcn_mfma_f32_16x16x32_bf16(af[mt], bf[nt], acc[mt][nt], 0, 0, 0);
  }

#pragma unroll
  for (int mt = 0; mt < 4; ++mt)
#pragma unroll
    for (int nt = 0; nt < 4; ++nt)
#pragma unroll
      for (int r = 0; r < 4; ++r) {
        int row = tm + wm + mt * 16 + quad * 4 + r;
        int col = tn + wn + nt * 16 + l16;
        float v = acc[mt][nt][r];
        if (OUT_BF16) ((unsigned short*)Cv)[(size_t)row * N + col] = f2bf(v);
        else          ((float*)Cv)[(size_t)row * N + col] = v;
      }
}

// ---------------- in-place RoPE, dword-packed (one bf16 pair per thread-iter) ----------------
// Q dwords 0..1023 (scaled by 1/sqrt(HD)), K dwords 1024..1535. Pair i within head = d&63.
__global__ __launch_bounds__(256) void rope_k(unsigned short* __restrict__ qkv,
                                              const float* __restrict__ freqs) {
  const int bs = blockIdx.x;          // b*2048 + s
  const int s = bs & 2047;
  const float qscale = 0.08838834764831845f;  // 1/sqrt(128)
  unsigned int* row = (unsigned int*)(qkv + (size_t)bs * 4096);
  const float2* fr2 = (const float2*)(freqs + s * 128);
#pragma unroll
  for (int k = 0; k < 6; ++k) {
    int d = threadIdx.x + k * 256;           // dword index 0..1535
    float sc = (d < 1024) ? qscale : 1.0f;
    float2 cs = fr2[d & 63];                 // (cos, sin)
    unsigned int w = row[d];
    float x0 = b2f((unsigned short)(w & 0xffffu));
    float x1 = b2f((unsigned short)(w >> 16));
    float y0 = (x0 * cs.y - x1 * cs.x) * sc;
    float y1 = (x0 * cs.x + x1 * cs.y) * sc;
    row[d] = ((unsigned int)f2bf(y1) << 16) | (unsigned int)f2bf(y0);
  }
}

// ---------------- V transpose: QKV V-cols (b,s,kv,d) -> Vt[(b*8+kv), d, s] ----------------
__global__ __launch_bounds__(256) void transpose_v(const unsigned short* __restrict__ qkv,
                                                   unsigned short* __restrict__ vt) {
  __shared__ unsigned short tile[64][65];
  const int s0 = blockIdx.x * 64, d0 = blockIdx.y * 64;
  const int bk = blockIdx.z; const int b = bk >> 3, kv = bk & 7;
  const int t = threadIdx.x;
#pragma unroll
  for (int i = 0; i < 16; ++i) {
    int idx = t + i * 256; int r = idx >> 6, c = idx & 63;
    tile[r][c] = qkv[(size_t)(b * 2048 + s0 + r) * 4096 + 3072 + kv * 128 + d0 + c];
  }
  __syncthreads();
#pragma unroll
  for (int i = 0; i < 16; ++i) {
    int idx = t + i * 256; int r = idx >> 6, c = idx & 63;
    vt[((size_t)bk * 128 + d0 + r) * 2048 + s0 + c] = tile[c][r];
  }
}

// ---------------- causal flash attention, S^T formulation ----------------
// grid: (16, H, B); block does q-tiles {j, 31-j} (uniform 33 iters). 4 waves; wave w owns
// q rows qtile*64 + w*16 .. +15. LDS K/V tiles chunk-swizzled (chunk ^= row & (nchunk-1)).
__global__ __launch_bounds__(256) void attn_k(const unsigned short* __restrict__ qkv,
                                              const unsigned short* __restrict__ vt,
                                              unsigned short* __restrict__ Ob) {
  __shared__ __align__(16) unsigned short Ks[64 * 128];   // [key][d], 16 chunks/row
  __shared__ __align__(16) unsigned short Vs[128 * 64];   // [d][key],  8 chunks/row
  __shared__ __align__(16) unsigned short Ps[4][16 * 64]; // per-wave P [qrow][key], 8 chunks/row
  const int t = threadIdx.x, wave = t >> 6, lane = t & 63, quad = lane >> 4, l16 = lane & 15;
  const int jpair = blockIdx.x, h = blockIdx.y, b = blockIdx.z;
  const int kv = h >> 1;

  for (int pass = 0; pass < 2; ++pass) {
    const int qblk = (pass == 0) ? jpair : 31 - jpair;
    const int q0 = qblk * 64;

    short8 qf[4];
    {
      const unsigned short* qp =
          qkv + (size_t)(b * 2048 + q0 + wave * 16 + l16) * 4096 + h * 128 + quad * 8;
#pragma unroll
      for (int kc = 0; kc < 4; ++kc) qf[kc] = *(const short8*)(qp + kc * 32);
    }
    v4f oa[8];
#pragma unroll
    for (int i = 0; i < 8; ++i) oa[i] = (v4f){0.f, 0.f, 0.f, 0.f};
    float m_s = -3.0e38f, l_s = 0.f;   // softmax state for qrow = q0 + wave*16 + l16

    for (int jt = 0; jt <= qblk; ++jt) {
      __syncthreads();   // previous iter/pass done reading Ks/Vs
#pragma unroll
      for (int issue = 0; issue < 4; ++issue) {
        int s = issue * 256 + t;
        // K: slot row = s>>4, phys chunk = s&15, source chunk = (s&15)^(row&15)
        gl_lds16(qkv + (size_t)(b * 2048 + jt * 64 + (s >> 4)) * 4096 + 2048 + kv * 128 +
                     (((s & 15) ^ ((s >> 4) & 15)) * 8),
                 Ks + (issue * 256 + wave * 64) * 8);
        // V: slot row(d) = s>>3, phys chunk = s&7, source chunk = (s&7)^(row&7)
        gl_lds16(vt + ((size_t)(b * 8 + kv) * 128 + (s >> 3)) * 2048 + jt * 64 +
                     (((s & 7) ^ ((s >> 3) & 7)) * 8),
                 Vs + (issue * 256 + wave * 64) * 8);
      }
      __syncthreads();

      // S^T = K * Q^T : st[mt] C-layout row=key mt*16+quad*4+r, col=qrow l16
      v4f st[4];
#pragma unroll
      for (int mt = 0; mt < 4; ++mt) st[mt] = (v4f){0.f, 0.f, 0.f, 0.f};
#pragma unroll
      for (int kc = 0; kc < 4; ++kc)
#pragma unroll
        for (int mt = 0; mt < 4; ++mt) {
          short8 kf = *(const short8*)(Ks + (mt * 16 + l16) * 128 + (((kc * 4 + quad) ^ l16) * 8));
          st[mt] = __builtin_amdgcn_mfma_f32_16x16x32_bf16(kf, qf[kc], st[mt], 0, 0, 0);
        }

      // masking (diag tile only) + per-lane max over 16 key values
      const bool diag = (jt == qblk);
      float mx = -3.0e38f;
#pragma unroll
      for (int mt = 0; mt < 4; ++mt)
#pragma unroll
        for (int r = 0; r < 4; ++r) {
          float v = st[mt][r];
          if (diag && (mt * 16 + quad * 4 + r > wave * 16 + l16)) v = -1.0e30f;
          st[mt][r] = v;
          mx = fmaxf(mx, v);
        }
      mx = fmaxf(mx, __shfl_xor(mx, 16));
      mx = fmaxf(mx, __shfl_xor(mx, 32));
      float mn = fmaxf(m_s, mx);
      float alpha = exp2f((m_s - mn) * LOG2E);
      m_s = mn;
      float lt = 0.f;
#pragma unroll
      for (int mt = 0; mt < 4; ++mt)
#pragma unroll
        for (int r = 0; r < 4; ++r) {
          float p = exp2f((st[mt][r] - mn) * LOG2E);
          st[mt][r] = p;
          lt += p;
        }
      lt += __shfl_xor(lt, 16);
      lt += __shfl_xor(lt, 32);
      l_s = l_s * alpha + lt;

      // rescale O accumulator: alpha indexed by qrow_rel; oa rows are quad*4+r
      float a_q[4];
#pragma unroll
      for (int r = 0; r < 4; ++r) a_q[r] = __shfl(alpha, quad * 4 + r);
#pragma unroll
      for (int nt = 0; nt < 8; ++nt)
#pragma unroll
        for (int r = 0; r < 4; ++r) oa[nt][r] *= a_q[r];

      // P^T (C-layout) -> P [qrow][key] in LDS, packed b64 writes, swizzled
#pragma unroll
      for (int mt = 0; mt < 4; ++mt) {
        int pcp = ((mt * 2 + (quad >> 1)) ^ (l16 & 7));
        ushort4 w;
        w.x = f2bf(st[mt][0]); w.y = f2bf(st[mt][1]);
        w.z = f2bf(st[mt][2]); w.w = f2bf(st[mt][3]);
        *(ushort4*)(&Ps[wave][l16 * 64 + pcp * 8 + (quad & 1) * 4]) = w;
      }
      asm volatile("s_waitcnt lgkmcnt(0)" ::: "memory");   // same-wave DS ordering

      short8 pf[2];
#pragma unroll
      for (int kc2 = 0; kc2 < 2; ++kc2)
        pf[kc2] = *(const short8*)(&Ps[wave][l16 * 64 + (((kc2 * 4 + quad) ^ (l16 & 7)) * 8)]);
#pragma unroll
      for (int nt = 0; nt < 8; ++nt)
#pragma unroll
        for (int kc2 = 0; kc2 < 2; ++kc2) {
          short8 vf = *(const short8*)(Vs + (nt * 16 + l16) * 64 +
                                       (((kc2 * 4 + quad) ^ (l16 & 7)) * 8));
          oa[nt] = __builtin_amdgcn_mfma_f32_16x16x32_bf16(pf[kc2], vf, oa[nt], 0, 0, 0);
        }
    }

    // epilogue: l indexed by qrow_rel (l16 lane-space) -> rows quad*4+r
    float inv[4];
#pragma unroll
    for (int r = 0; r < 4; ++r) inv[r] = 1.0f / __shfl(l_s, quad * 4 + r);
#pragma unroll
    for (int r = 0; r < 4; ++r) {
      int row = b * 2048 + q0 + wave * 16 + quad * 4 + r;
#pragma unroll
      for (int nt = 0; nt < 8; ++nt)
        Ob[(size_t)row * 2048 + h * 128 + nt * 16 + l16] = f2bf(oa[nt][r] * inv[r]);
    }
    __syncthreads();   // protect Ks/Vs before next pass begins staging
  }
}

extern "C" void kernel_launch(void* const* d_in, const int* in_sizes, int n_in,
                              void* d_out, int out_size, void* d_ws, size_t ws_size,
                              hipStream_t stream) {
  (void)in_sizes; (void)n_in; (void)out_size; (void)ws_size;
  const float* x  = (const float*)d_in[0];
  const float* fr = (const float*)d_in[1];
  // d_in[2] = mask: implemented as causal directly
  const float* wq = (const float*)d_in[3];
  const float* wk = (const float*)d_in[4];
  const float* wv = (const float*)d_in[5];
  const float* wo = (const float*)d_in[6];
  float* out = (float*)d_out;

  char* ws = (char*)d_ws;
  unsigned short* Xb    = (unsigned short*)(ws);                      // 16 MB
  unsigned short* WqkvT = (unsigned short*)(ws + (size_t)(16u << 20));// 16 MB, [n][k]
  unsigned short* WoT   = (unsigned short*)(ws + (size_t)(32u << 20));// 8 MB
  unsigned short* QKV   = (unsigned short*)(ws + (size_t)(40u << 20));// 32 MB (4096 x 4096)
  unsigned short* Vt    = (unsigned short*)(ws);                      // reuse Xb region
  unsigned short* Ob    = (unsigned short*)(ws + (size_t)(16u << 20));// reuse WqkvT region

  cvt_f32_bf16<<<8192, 256, 0, stream>>>(x, Xb, 2 * 2048 * 2048);
  transpose_f32_bf16<<<dim3(32, 32), 256, 0, stream>>>(wq, WqkvT, 2048);
  transpose_f32_bf16<<<dim3(16, 32), 256, 0, stream>>>(wk, WqkvT + (size_t)2048 * 2048, 1024);
  transpose_f32_bf16<<<dim3(16, 32), 256, 0, stream>>>(wv, WqkvT + (size_t)3072 * 2048, 1024);
  transpose_f32_bf16<<<dim3(32, 32), 256, 0, stream>>>(wo, WoT, 2048);
  gemm_bt<true><<<dim3(32, 32), 256, 0, stream>>>(Xb, WqkvT, QKV, 4096, 4096, 2048);
  rope_k<<<4096, 256, 0, stream>>>(QKV, fr);
  transpose_v<<<dim3(32, 2, 16), 256, 0, stream>>>(QKV, Vt);
  attn_k<<<dim3(16, 16, 2), 256, 0, stream>>>(QKV, Vt, Ob);
  gemm_bt<false><<<dim3(16, 32), 256, 0, stream>>>(Ob, WoT, out, 4096, 2048, 2048);
}